// Round 4
// baseline (426.279 us; speedup 1.0000x reference)
//
#include <hip/hip_runtime.h>
#include <math.h>

#define TPB 256
#define NBLOCKS 2048
#define LUTN 1032

typedef float v4f __attribute__((ext_vector_type(4)));

__device__ __forceinline__ float fsqrt_(float x){ return __builtin_amdgcn_sqrtf(x); }
__device__ __forceinline__ float frcp_ (float x){ return __builtin_amdgcn_rcpf(x); }
__device__ __forceinline__ float frsq_ (float x){ return __builtin_amdgcn_rsqf(x); }
__device__ __forceinline__ float flog2_(float x){ return __builtin_amdgcn_logf(x); }   // v_log_f32
__device__ __forceinline__ float fexp2_(float x){ return __builtin_amdgcn_exp2f(x); }  // v_exp_f32
__device__ __forceinline__ float fsinr_(float x){ return __builtin_amdgcn_sinf(x); }   // v_sin_f32, REVOLUTIONS
__device__ __forceinline__ float ffract_(float x){ return x - floorf(x); }             // folds to v_fract_f32

__device__ __forceinline__ v4f vs(float x){ return (v4f){x, x, x, x}; }

#define V4APPLY(fn, a) ((v4f){ fn((a).x), fn((a).y), fn((a).z), fn((a).w) })
__device__ __forceinline__ v4f vsqrt(v4f a){ return V4APPLY(fsqrt_, a); }
__device__ __forceinline__ v4f vrcp (v4f a){ return V4APPLY(frcp_ , a); }
__device__ __forceinline__ v4f vrsq (v4f a){ return V4APPLY(frsq_ , a); }
__device__ __forceinline__ v4f vsinr(v4f a){ return V4APPLY(fsinr_, a); }

#if __has_builtin(__builtin_elementwise_fma)
__device__ __forceinline__ v4f vfma(v4f a, v4f b, v4f c){ return __builtin_elementwise_fma(a,b,c); }
#else
__device__ __forceinline__ v4f vfma(v4f a, v4f b, v4f c){ return a*b + c; }
#endif
__device__ __forceinline__ v4f vmax(v4f a, v4f b){ return __builtin_elementwise_max(a,b); }
__device__ __forceinline__ v4f vmin(v4f a, v4f b){ return __builtin_elementwise_min(a,b); }
__device__ __forceinline__ v4f vabs(v4f a){ return __builtin_elementwise_abs(a); }
__device__ __forceinline__ v4f vselgt(v4f x, float t, v4f a, v4f b){
    v4f r;
    r.x = x.x > t ? a.x : b.x;
    r.y = x.y > t ? a.y : b.y;
    r.z = x.z > t ? a.z : b.z;
    r.w = x.w > t ? a.w : b.w;
    return r;
}
__device__ __forceinline__ v4f vcopysign(v4f m, v4f s){
    v4f r;
    r.x = copysignf(m.x, s.x);
    r.y = copysignf(m.y, s.y);
    r.z = copysignf(m.z, s.z);
    r.w = copysignf(m.w, s.w);
    return r;
}

// LUT with linear interp. v = x*1024, guaranteed in [0, LUTN-2).
__device__ __forceinline__ float lut1(const float* __restrict__ lut, float v){
    int i = (int)v;
    float f = ffract_(v);
    float a = lut[i], b = lut[i+1];     // -> ds_read2_b32
    return fmaf(f, b - a, a);
}
__device__ __forceinline__ v4f vlut(const float* __restrict__ lut, v4f v){
    return (v4f){ lut1(lut, v.x), lut1(lut, v.y), lut1(lut, v.z), lut1(lut, v.w) };
}

// sRGB->Lab via LUTs. XYZ_REF folded into matrix; x1024 folded so xyz are direct indices.
__device__ __forceinline__ void rgb2lab(const float* __restrict__ lutS, const float* __restrict__ lutF,
                                        v4f r, v4f g, v4f b, v4f& L, v4f& A, v4f& Bv){
    v4f lr = vlut(lutS, r * vs(1024.0f));
    v4f lg = vlut(lutS, g * vs(1024.0f));
    v4f lb = vlut(lutS, b * vs(1024.0f));
    v4f xi = vfma(vs(444.364687f), lr, vfma(vs(385.238808f), lg, vs(194.397593f)*lb));
    v4f yi = vfma(vs(217.777050f), lr, vfma(vs(732.315853f), lg, vs( 73.907200f)*lb));
    v4f zi = vfma(vs( 18.182738f), lr, vfma(vs(112.095395f), lg, vs(893.719306f)*lb));
    v4f fx = vlut(lutF, xi), fy = vlut(lutF, yi), fz = vlut(lutF, zi);
    L  = vfma(vs(116.0f), fy, vs(-16.0f));
    A  = vs(500.0f) * (fx - fy);
    Bv = vs(200.0f) * (fy - fz);
}

// atan2(y,x) mod 2pi in [0,2pi); minimax atan on [0,1], |err|~1e-6 rad.
__device__ __forceinline__ v4f vatan2_2pi(v4f y, v4f x){
    v4f ax = vabs(x), ay = vabs(y);
    v4f mx = vmax(ax, ay), mn = vmin(ax, ay);
    v4f t = mn * vrcp(vmax(mx, vs(1e-38f)));
    v4f s = t * t;
    v4f p = vs(-0.01172120f);
    p = vfma(p, s, vs( 0.05265332f));
    p = vfma(p, s, vs(-0.11643287f));
    p = vfma(p, s, vs( 0.19354346f));
    p = vfma(p, s, vs(-0.33262347f));
    p = vfma(p, s, vs( 0.99997726f));
    p = p * t;
    v4f r = vselgt(ay - ax, 0.0f, vs(1.57079632679f) - p, p);
    r = vselgt(vs(0.0f) - x, 0.0f, vs(3.14159265359f) - r, r);
    r = vselgt(vs(0.0f) - y, 0.0f, vs(6.28318530718f) - r, r);
    return r;
}

__device__ __forceinline__ v4f row_loss(const float* __restrict__ lutS, const float* __restrict__ lutF,
                                        v4f pr, v4f pg, v4f pb,
                                        v4f tr, v4f tg, v4f tb){
    const float P257 = 6103515625.0f;   // 25^7

    v4f dr = pr - tr, dg = pg - tg, db = pb - tb;
    v4f mse = (dr*dr + dg*dg + db*db) * vs(1.0f/3.0f);

    v4f L1, a1, b1, L2, a2, b2;
    rgb2lab(lutS, lutF, pr, pg, pb, L1, a1, b1);
    rgb2lab(lutS, lutF, tr, tg, tb, L2, a2, b2);

    v4f C1 = vsqrt(vfma(a1, a1, b1*b1));
    v4f C2 = vsqrt(vfma(a2, a2, b2*b2));
    v4f Cav = vs(0.5f) * (C1 + C2);
    v4f c2v = Cav*Cav;
    v4f c7 = c2v*c2v*c2v*Cav;
    // sqrt(c7/(c7+P)) == c7 * rsq(c7*(c7+P))  (1 trans instead of 2)
    v4f gs = c7 * vrsq(vmax(c7*(c7 + vs(P257)), vs(1e-30f)));
    v4f opG = vfma(vs(-0.5f), gs, vs(1.5f));      // 1+G
    v4f a1p = a1 * opG;
    v4f a2p = a2 * opG;
    v4f C1p = vsqrt(vfma(a1p, a1p, b1*b1));
    v4f C2p = vsqrt(vfma(a2p, a2p, b2*b2));

    v4f dL = L2 - L1;
    v4f dC = C2p - C1p;

    // chord form of dH (exact incl. wraparound; sign = sign of 2D cross)
    v4f prod  = C1p * C2p;
    v4f dot   = vfma(a1p, a2p, b1*b2);
    v4f cross = vfma(a1p, b2, vs(0.0f) - a2p*b1);
    v4f dH = vcopysign(vsqrt(vmax(vs(2.0f)*(prod - dot), vs(0.0f))), cross);

    v4f Lav  = vs(0.5f) * (L1 + L2);
    v4f Cpav = vs(0.5f) * (C1p + C2p);

    // h_avg direction via vector sum (handles wraparound without branches)
    v4f vx = vfma(a1p, C2p, a2p*C1p);
    v4f vy = vfma(b1 , C2p, b2 *C1p);
    v4f hav = vatan2_2pi(vy, vx);                    // only for the theta Gaussian
    v4f inv = vrsq(vmax(vfma(vx, vx, vy*vy), vs(1e-30f)));
    v4f ch = vx * inv, sh = vy * inv;                // cos/sin(h_avg)

    // T via multiple-angle identities (0 trans)
    v4f cos2 = vfma(vs(2.0f)*ch, ch, vs(-1.0f));
    v4f sin2 = vs(2.0f) * sh * ch;
    v4f cos3 = ch * vfma(vs(2.0f), cos2, vs(-1.0f));
    v4f sin3 = sh * vfma(vs(2.0f), cos2, vs( 1.0f));
    v4f cos4 = vfma(vs(2.0f)*cos2, cos2, vs(-1.0f));
    v4f sin4 = vs(2.0f) * sin2 * cos2;
    v4f T = vs(1.0f);
    T = vfma(vs(-0.147224319f), ch,   T);
    T = vfma(vs(-0.085f),       sh,   T);
    T = vfma(vs( 0.24f),        cos2, T);
    T = vfma(vs( 0.318247006f), cos3, T);
    T = vfma(vs(-0.033449109f), sin3, T);
    T = vfma(vs(-0.090798100f), cos4, T);
    T = vfma(vs(-0.178201305f), sin4, T);

    // theta = 30*exp(-((deg-275)/25)^2)
    v4f u = vfma(hav, vs(2.29183118f), vs(-11.0f));
    v4f theta = vs(30.0f) * V4APPLY(fexp2_, (vs(-1.44269504f) * (u*u)));

    v4f cp2 = Cpav*Cpav;
    v4f cp7 = cp2*cp2*cp2*Cpav;
    v4f RC = vs(2.0f) * (cp7 * vrsq(vmax(cp7*(cp7 + vs(P257)), vs(1e-30f))));
    v4f RT = vs(0.0f) - vsinr(theta * vs(0.31830988618f)) * RC;   // sin(2θ), revolutions

    v4f Lm = Lav - vs(50.0f);
    v4f Lm2 = Lm * Lm;
    v4f SL = vfma(vs(0.015f) * Lm2, vrsq(vs(20.0f) + Lm2), vs(1.0f));
    v4f SC = vfma(vs(0.045f), Cpav, vs(1.0f));
    v4f SH = vfma(vs(0.015f) * Cpav, T, vs(1.0f));

    // one rcp for all three quotients
    v4f SCSH = SC * SH;
    v4f SLSH = SL * SH;
    v4f SLSC = SL * SC;
    v4f R = vrcp(SLSC * SH);
    v4f t1 = dL * (SCSH * R);
    v4f t2 = dC * (SLSH * R);
    v4f t3 = dH * (SLSC * R);
    v4f arg = vfma(t1, t1, vfma(t2, t2, vfma(t3, t3, RT*t2*t3)));
    v4f de = vsqrt(vmax(arg, vs(0.0f)));

    return vfma(vs(0.2f), mse, vs(0.8f) * de);
}

__global__ void __launch_bounds__(TPB)
de_main(const float* __restrict__ pred, const float* __restrict__ tgt,
        float* __restrict__ partials, int B){
    __shared__ float lutS[LUTN];
    __shared__ float lutF[LUTN];
    for (int i = threadIdx.x; i < LUTN; i += TPB){
        float c = (float)i * (1.0f/1024.0f);
        float p = fexp2_(2.4f * flog2_((c + 0.055f) * (1.0f/1.055f)));
        lutS[i] = (c > 0.04045f) ? p : c * (1.0f/12.92f);
        float cb = fexp2_((1.0f/3.0f) * flog2_(fmaxf(c, 1e-20f)));
        lutF[i] = (c > 0.008856f) ? cb : fmaf(7.787f, c, 16.0f/116.0f);
    }
    __syncthreads();

    int nvec = B >> 2;                 // groups of 4 rows = 3 float4
    int gid = blockIdx.x * TPB + threadIdx.x;
    int stride = gridDim.x * TPB;
    v4f acc4 = vs(0.0f);

    for (int i = gid; i < nvec; i += stride){
        const float4* p4 = (const float4*)pred + (size_t)i * 3;
        const float4* t4 = (const float4*)tgt  + (size_t)i * 3;
        float4 pA = p4[0], pB = p4[1], pC = p4[2];
        float4 tA = t4[0], tB = t4[1], tC = t4[2];
        v4f pr = (v4f){pA.x, pA.w, pB.z, pC.y};
        v4f pg = (v4f){pA.y, pB.x, pB.w, pC.z};
        v4f pb = (v4f){pA.z, pB.y, pC.x, pC.w};
        v4f qr = (v4f){tA.x, tA.w, tB.z, tC.y};
        v4f qg = (v4f){tA.y, tB.x, tB.w, tC.z};
        v4f qb = (v4f){tA.z, tB.y, tC.x, tC.w};
        acc4 += row_loss(lutS, lutF, pr, pg, pb, qr, qg, qb);
    }
    float acc = acc4.x + acc4.y + acc4.z + acc4.w;

    int r = (nvec << 2) + gid;          // tail rows (B % 4), at most 3
    if (r < B){
        v4f pr = vs(pred[(size_t)r*3]), pg = vs(pred[(size_t)r*3+1]), pb = vs(pred[(size_t)r*3+2]);
        v4f qr = vs(tgt [(size_t)r*3]), qg = vs(tgt [(size_t)r*3+1]), qb = vs(tgt [(size_t)r*3+2]);
        acc += row_loss(lutS, lutF, pr, pg, pb, qr, qg, qb).x;
    }

    __shared__ float sdata[TPB];
    sdata[threadIdx.x] = acc;
    __syncthreads();
    #pragma unroll
    for (int s = TPB/2; s > 0; s >>= 1){
        if (threadIdx.x < s) sdata[threadIdx.x] += sdata[threadIdx.x + s];
        __syncthreads();
    }
    if (threadIdx.x == 0) partials[blockIdx.x] = sdata[0];
}

__global__ void __launch_bounds__(TPB)
de_final(const float* __restrict__ partials, int n, float* __restrict__ out, double invB){
    __shared__ double sd[TPB];
    double acc = 0.0;
    for (int i = threadIdx.x; i < n; i += TPB) acc += (double)partials[i];
    sd[threadIdx.x] = acc;
    __syncthreads();
    #pragma unroll
    for (int s = TPB/2; s > 0; s >>= 1){
        if (threadIdx.x < s) sd[threadIdx.x] += sd[threadIdx.x + s];
        __syncthreads();
    }
    if (threadIdx.x == 0) out[0] = (float)(sd[0] * invB);
}

extern "C" void kernel_launch(void* const* d_in, const int* in_sizes, int n_in,
                              void* d_out, int out_size, void* d_ws, size_t ws_size,
                              hipStream_t stream){
    const float* pred = (const float*)d_in[0];
    const float* tgt  = (const float*)d_in[1];
    int B = in_sizes[0] / 3;

    int nvec = B >> 2;
    int blocks = (nvec + TPB - 1) / TPB;
    if (blocks > NBLOCKS) blocks = NBLOCKS;
    size_t wcap = ws_size / sizeof(float);
    if (wcap > 0 && (size_t)blocks > wcap) blocks = (int)wcap;
    if (blocks < 1) blocks = 1;

    float* partials = (float*)d_ws;
    de_main <<<blocks, TPB, 0, stream>>>(pred, tgt, partials, B);
    de_final<<<1, TPB, 0, stream>>>(partials, blocks, (float*)d_out, 1.0/(double)B);
}

// Round 5
// 421.692 us; speedup vs baseline: 1.0109x; 1.0109x over previous
//
#include <hip/hip_runtime.h>
#include <math.h>

#define TPB 256
#define NBLOCKS 2048

typedef float v4f __attribute__((ext_vector_type(4)));

__device__ __forceinline__ float fsqrt_(float x){ return __builtin_amdgcn_sqrtf(x); }
__device__ __forceinline__ float frcp_ (float x){ return __builtin_amdgcn_rcpf(x); }
__device__ __forceinline__ float frsq_ (float x){ return __builtin_amdgcn_rsqf(x); }
__device__ __forceinline__ float flog2_(float x){ return __builtin_amdgcn_logf(x); }   // v_log_f32
__device__ __forceinline__ float fexp2_(float x){ return __builtin_amdgcn_exp2f(x); }  // v_exp_f32
__device__ __forceinline__ float fsinr_(float x){ return __builtin_amdgcn_sinf(x); }   // v_sin_f32, REVOLUTIONS

__device__ __forceinline__ v4f vs(float x){ return (v4f){x, x, x, x}; }

#define V4APPLY(fn, a) ((v4f){ fn((a).x), fn((a).y), fn((a).z), fn((a).w) })
__device__ __forceinline__ v4f vsqrt(v4f a){ return V4APPLY(fsqrt_, a); }
__device__ __forceinline__ v4f vrcp (v4f a){ return V4APPLY(frcp_ , a); }
__device__ __forceinline__ v4f vrsq (v4f a){ return V4APPLY(frsq_ , a); }
__device__ __forceinline__ v4f vlog2(v4f a){ return V4APPLY(flog2_, a); }
__device__ __forceinline__ v4f vexp2(v4f a){ return V4APPLY(fexp2_, a); }
__device__ __forceinline__ v4f vsinr(v4f a){ return V4APPLY(fsinr_, a); }

#if __has_builtin(__builtin_elementwise_fma)
__device__ __forceinline__ v4f vfma(v4f a, v4f b, v4f c){ return __builtin_elementwise_fma(a,b,c); }
#else
__device__ __forceinline__ v4f vfma(v4f a, v4f b, v4f c){ return a*b + c; }
#endif
__device__ __forceinline__ v4f vmax(v4f a, v4f b){ return __builtin_elementwise_max(a,b); }
__device__ __forceinline__ v4f vmin(v4f a, v4f b){ return __builtin_elementwise_min(a,b); }
__device__ __forceinline__ v4f vabs(v4f a){ return __builtin_elementwise_abs(a); }
__device__ __forceinline__ v4f vselgt(v4f x, float t, v4f a, v4f b){
    v4f r;
    r.x = x.x > t ? a.x : b.x;
    r.y = x.y > t ? a.y : b.y;
    r.z = x.z > t ? a.z : b.z;
    r.w = x.w > t ? a.w : b.w;
    return r;
}
__device__ __forceinline__ v4f vcopysign(v4f m, v4f s){
    v4f r;
    r.x = copysignf(m.x, s.x);
    r.y = copysignf(m.y, s.y);
    r.z = copysignf(m.z, s.z);
    r.w = copysignf(m.w, s.w);
    return r;
}

__device__ __forceinline__ v4f srgb_lin(v4f c){
    v4f t = (c + vs(0.055f)) * vs(1.0f/1.055f);
    v4f p = vexp2(vs(2.4f) * vlog2(t));
    return vselgt(c, 0.04045f, p, c * vs(1.0f/12.92f));
}
__device__ __forceinline__ v4f lab_f(v4f t){
    v4f cb = vexp2(vs(1.0f/3.0f) * vlog2(t));
    return vselgt(t, 0.008856f, cb, vfma(vs(7.787f), t, vs(16.0f/116.0f)));
}

// XYZ_REF divides folded into matrix rows.
__device__ __forceinline__ void rgb2lab(v4f r, v4f g, v4f b, v4f& L, v4f& A, v4f& Bv){
    v4f lr = srgb_lin(r), lg = srgb_lin(g), lb = srgb_lin(b);
    v4f xn = vfma(vs(0.4339499f), lr, vfma(vs(0.3762098f), lg, vs(0.1898414f)*lb));
    v4f yn = vfma(vs(0.2126729f), lr, vfma(vs(0.7151522f), lg, vs(0.0721750f)*lb));
    v4f zn = vfma(vs(0.0177566f), lr, vfma(vs(0.1094680f), lg, vs(0.8727720f)*lb));
    v4f fx = lab_f(xn), fy = lab_f(yn), fz = lab_f(zn);
    L  = vfma(vs(116.0f), fy, vs(-16.0f));
    A  = vs(500.0f) * (fx - fy);
    Bv = vs(200.0f) * (fy - fz);
}

// atan2(y,x) mod 2pi in [0,2pi); minimax atan on [0,1], |err|~1e-6 rad.
__device__ __forceinline__ v4f vatan2_2pi(v4f y, v4f x){
    v4f ax = vabs(x), ay = vabs(y);
    v4f mx = vmax(ax, ay), mn = vmin(ax, ay);
    v4f t = mn * vrcp(vmax(mx, vs(1e-38f)));
    v4f s = t * t;
    v4f p = vs(-0.01172120f);
    p = vfma(p, s, vs( 0.05265332f));
    p = vfma(p, s, vs(-0.11643287f));
    p = vfma(p, s, vs( 0.19354346f));
    p = vfma(p, s, vs(-0.33262347f));
    p = vfma(p, s, vs( 0.99997726f));
    p = p * t;
    v4f r = vselgt(ay - ax, 0.0f, vs(1.57079632679f) - p, p);
    r = vselgt(vs(0.0f) - x, 0.0f, vs(3.14159265359f) - r, r);
    r = vselgt(vs(0.0f) - y, 0.0f, vs(6.28318530718f) - r, r);
    return r;
}

__device__ __forceinline__ v4f row_loss(v4f pr, v4f pg, v4f pb,
                                        v4f tr, v4f tg, v4f tb){
    const float P257 = 6103515625.0f;   // 25^7

    v4f dr = pr - tr, dg = pg - tg, db = pb - tb;
    v4f mse = (dr*dr + dg*dg + db*db) * vs(1.0f/3.0f);

    v4f L1, a1, b1, L2, a2, b2;
    rgb2lab(pr, pg, pb, L1, a1, b1);
    rgb2lab(tr, tg, tb, L2, a2, b2);

    v4f C1 = vsqrt(vfma(a1, a1, b1*b1));
    v4f C2 = vsqrt(vfma(a2, a2, b2*b2));
    v4f Cav = vs(0.5f) * (C1 + C2);
    v4f c2v = Cav*Cav;
    v4f c7 = c2v*c2v*c2v*Cav;
    // sqrt(c7/(c7+P)) == c7 * rsq(c7*(c7+P))  (1 trans instead of 2)
    v4f gs = c7 * vrsq(vmax(c7*(c7 + vs(P257)), vs(1e-30f)));
    v4f opG = vfma(vs(-0.5f), gs, vs(1.5f));      // 1+G
    v4f a1p = a1 * opG;
    v4f a2p = a2 * opG;
    v4f C1p = vsqrt(vfma(a1p, a1p, b1*b1));
    v4f C2p = vsqrt(vfma(a2p, a2p, b2*b2));

    v4f dL = L2 - L1;
    v4f dC = C2p - C1p;

    // chord form of dH (exact incl. wraparound; sign = sign of 2D cross)
    v4f prod  = C1p * C2p;
    v4f dot   = vfma(a1p, a2p, b1*b2);
    v4f cross = vfma(a1p, b2, vs(0.0f) - a2p*b1);
    v4f dH = vcopysign(vsqrt(vmax(vs(2.0f)*(prod - dot), vs(0.0f))), cross);

    v4f Lav  = vs(0.5f) * (L1 + L2);
    v4f Cpav = vs(0.5f) * (C1p + C2p);

    // h_avg direction via vector sum (handles wraparound without branches)
    v4f vx = vfma(a1p, C2p, a2p*C1p);
    v4f vy = vfma(b1 , C2p, b2 *C1p);
    v4f hav = vatan2_2pi(vy, vx);                    // only for the theta Gaussian
    v4f inv = vrsq(vmax(vfma(vx, vx, vy*vy), vs(1e-30f)));
    v4f ch = vx * inv, sh = vy * inv;                // cos/sin(h_avg)

    // T via multiple-angle identities (0 trans)
    v4f cos2 = vfma(vs(2.0f)*ch, ch, vs(-1.0f));
    v4f sin2 = vs(2.0f) * sh * ch;
    v4f cos3 = ch * vfma(vs(2.0f), cos2, vs(-1.0f));
    v4f sin3 = sh * vfma(vs(2.0f), cos2, vs( 1.0f));
    v4f cos4 = vfma(vs(2.0f)*cos2, cos2, vs(-1.0f));
    v4f sin4 = vs(2.0f) * sin2 * cos2;
    v4f T = vs(1.0f);
    T = vfma(vs(-0.147224319f), ch,   T);
    T = vfma(vs(-0.085f),       sh,   T);
    T = vfma(vs( 0.24f),        cos2, T);
    T = vfma(vs( 0.318247006f), cos3, T);
    T = vfma(vs(-0.033449109f), sin3, T);
    T = vfma(vs(-0.090798100f), cos4, T);
    T = vfma(vs(-0.178201305f), sin4, T);

    // theta = 30*exp(-((deg-275)/25)^2)
    v4f u = vfma(hav, vs(2.29183118f), vs(-11.0f));
    v4f theta = vs(30.0f) * vexp2(vs(-1.44269504f) * (u*u));

    v4f cp2 = Cpav*Cpav;
    v4f cp7 = cp2*cp2*cp2*Cpav;
    v4f RC = vs(2.0f) * (cp7 * vrsq(vmax(cp7*(cp7 + vs(P257)), vs(1e-30f))));
    v4f RT = vs(0.0f) - vsinr(theta * vs(0.31830988618f)) * RC;   // sin(2θ), revolutions

    v4f Lm = Lav - vs(50.0f);
    v4f Lm2 = Lm * Lm;
    v4f SL = vfma(vs(0.015f) * Lm2, vrsq(vs(20.0f) + Lm2), vs(1.0f));
    v4f SC = vfma(vs(0.045f), Cpav, vs(1.0f));
    v4f SH = vfma(vs(0.015f) * Cpav, T, vs(1.0f));

    // one rcp for all three quotients
    v4f SCSH = SC * SH;
    v4f SLSH = SL * SH;
    v4f SLSC = SL * SC;
    v4f R = vrcp(SLSC * SH);
    v4f t1 = dL * (SCSH * R);
    v4f t2 = dC * (SLSH * R);
    v4f t3 = dH * (SLSC * R);
    v4f arg = vfma(t1, t1, vfma(t2, t2, vfma(t3, t3, RT*t2*t3)));
    v4f de = vsqrt(vmax(arg, vs(0.0f)));

    return vfma(vs(0.2f), mse, vs(0.8f) * de);
}

struct Quad { float4 a, b, c, d, e, f; };   // pred x3, tgt x3

__device__ __forceinline__ Quad load_quad(const float* __restrict__ pred,
                                          const float* __restrict__ tgt, int i){
    const float4* p4 = (const float4*)pred + (size_t)i * 3;
    const float4* t4 = (const float4*)tgt  + (size_t)i * 3;
    Quad q;
    q.a = p4[0]; q.b = p4[1]; q.c = p4[2];
    q.d = t4[0]; q.e = t4[1]; q.f = t4[2];
    return q;
}

__device__ __forceinline__ v4f quad_loss(const Quad& q){
    v4f pr = (v4f){q.a.x, q.a.w, q.b.z, q.c.y};
    v4f pg = (v4f){q.a.y, q.b.x, q.b.w, q.c.z};
    v4f pb = (v4f){q.a.z, q.b.y, q.c.x, q.c.w};
    v4f qr = (v4f){q.d.x, q.d.w, q.e.z, q.f.y};
    v4f qg = (v4f){q.d.y, q.e.x, q.e.w, q.f.z};
    v4f qb = (v4f){q.d.z, q.e.y, q.f.x, q.f.w};
    return row_loss(pr, pg, pb, qr, qg, qb);
}

__global__ void __launch_bounds__(TPB)
de_main(const float* __restrict__ pred, const float* __restrict__ tgt,
        float* __restrict__ partials, int B){
    int nvec = B >> 2;                 // groups of 4 rows = 3 float4
    int gid = blockIdx.x * TPB + threadIdx.x;
    int stride = gridDim.x * TPB;
    v4f acc4 = vs(0.0f);

    // software-pipelined grid-stride loop: prefetch i+stride while computing i
    int i = gid;
    bool valid = (i < nvec);
    Quad cur;
    if (valid) cur = load_quad(pred, tgt, i);
    #pragma unroll 1
    while (valid){
        int j = i + stride;
        bool jv = (j < nvec);
        Quad nxt;
        if (jv) nxt = load_quad(pred, tgt, j);   // issued before the long compute
        acc4 += quad_loss(cur);
        cur = nxt; i = j; valid = jv;
    }
    float acc = acc4.x + acc4.y + acc4.z + acc4.w;

    int r = (nvec << 2) + gid;          // tail rows (B % 4), at most 3
    if (r < B){
        v4f pr = vs(pred[(size_t)r*3]), pg = vs(pred[(size_t)r*3+1]), pb = vs(pred[(size_t)r*3+2]);
        v4f qr = vs(tgt [(size_t)r*3]), qg = vs(tgt [(size_t)r*3+1]), qb = vs(tgt [(size_t)r*3+2]);
        acc += row_loss(pr, pg, pb, qr, qg, qb).x;
    }

    __shared__ float sdata[TPB];
    sdata[threadIdx.x] = acc;
    __syncthreads();
    #pragma unroll
    for (int s = TPB/2; s > 0; s >>= 1){
        if (threadIdx.x < s) sdata[threadIdx.x] += sdata[threadIdx.x + s];
        __syncthreads();
    }
    if (threadIdx.x == 0) partials[blockIdx.x] = sdata[0];
}

__global__ void __launch_bounds__(TPB)
de_final(const float* __restrict__ partials, int n, float* __restrict__ out, double invB){
    __shared__ double sd[TPB];
    double acc = 0.0;
    for (int i = threadIdx.x; i < n; i += TPB) acc += (double)partials[i];
    sd[threadIdx.x] = acc;
    __syncthreads();
    #pragma unroll
    for (int s = TPB/2; s > 0; s >>= 1){
        if (threadIdx.x < s) sd[threadIdx.x] += sd[threadIdx.x + s];
        __syncthreads();
    }
    if (threadIdx.x == 0) out[0] = (float)(sd[0] * invB);
}

extern "C" void kernel_launch(void* const* d_in, const int* in_sizes, int n_in,
                              void* d_out, int out_size, void* d_ws, size_t ws_size,
                              hipStream_t stream){
    const float* pred = (const float*)d_in[0];
    const float* tgt  = (const float*)d_in[1];
    int B = in_sizes[0] / 3;

    int nvec = B >> 2;
    int blocks = (nvec + TPB - 1) / TPB;
    if (blocks > NBLOCKS) blocks = NBLOCKS;   // 2048 => exactly 8 iters/thread at B=16.7M
    size_t wcap = ws_size / sizeof(float);
    if (wcap > 0 && (size_t)blocks > wcap) blocks = (int)wcap;
    if (blocks < 1) blocks = 1;

    float* partials = (float*)d_ws;
    de_main <<<blocks, TPB, 0, stream>>>(pred, tgt, partials, B);
    de_final<<<1, TPB, 0, stream>>>(partials, blocks, (float*)d_out, 1.0/(double)B);
}